// Round 10
// baseline (70.904 us; speedup 1.0000x reference)
//
#include <hip/hip_runtime.h>

// Problem constants (from reference setup_inputs)
#define NN 8
#define CC 4
#define HH 64
#define WW 64
#define KK 5
#define FF 16
#define HO 60
#define WO 60
#define PP (KK * KK * CC) /* 100 */

typedef float v4f __attribute__((ext_vector_type(4)));

#define PQ_ELEMS (CC * KK * 64)  /* 1280 pixel quads */
#define LDS_TOT 1536             /* max(pq 1280+4 pad, reduction 1536) v4f = 24.6 KB */

// ws: wq[((ff*PP)+p)*16 + j], ff = fgh*2+fgl in 0..3 (feature quad f=4ff..4ff+3)
// j: [0..3]=e^k1[f], [4..7]=k1 e^k1, [8..11]=e^k2, [12..15]=k2 e^k2.
// One s_load_dwordx16 per (p, wave) feeds all 24 inner fmas.
__global__ void smorph_weights(const float* __restrict__ k1,
                               const float* __restrict__ k2,
                               float* __restrict__ wq) {
    int i = blockIdx.x * blockDim.x + threadIdx.x;
    if (i < 4 * PP * 16) {
        int idx16 = i >> 4;         // ff*PP + p
        int ff = idx16 / PP;
        int p = idx16 - ff * PP;
        int j = i & 15;
        int grp = j >> 2;           // 0:e^k1 1:k1e^k1 2:e^k2 3:k2e^k2
        int fi = j & 3;
        int f = ff * 4 + fi;
        const float* kp = (grp >> 1) ? k2 : k1;
        float kv = kp[p * FF + f];
        float e = __expf(kv);
        wq[i] = (grp & 1) ? kv * e : e;
    }
}

// Round-10: triangulation of R1/R7/R9 bodies shows R1/R9 LDS-pipe-bound
// (~12.5us of ds_read_b128, 80% = 4 wave-uniform weight quads/iter) and R7
// latency-bound when LDS halved at low occupancy. Fix both at once: weight
// reads move to the SCALAR pipe (readfirstlane'd base -> s_load_dwordx16,
// proven mechanism in R0), consumed as the single allowed SGPR operand of
// each v_fma_f32; loads batched per-kh (<=5 lgkm drain groups per wave, vs
// R0's 100 which made s_load lose). LDS holds pixels only; inner-loop LDS
// traffic drops 5x (125 -> 25 b128/wave). 960 blocks keep 30 waves/CU.
__global__ __launch_bounds__(512) void smorph_conv(
        const float* __restrict__ x, const float* __restrict__ wq,
        const float* __restrict__ bias, float* __restrict__ out) {
    __shared__ v4f lds[LDS_TOT];
    v4f* pq = lds; // [c][kh-row][64] pixel quads {e^x, x e^x, e^-x, -x e^-x}

    int b = blockIdx.x;  // 0..959 = (n, ho, f-half)
    int n = b / (HO * 2);
    int rem = b - n * (HO * 2);
    int ho = rem >> 1;
    int fgh = rem & 1;   // feature half: features 8*fgh .. 8*fgh+7
    int t = threadIdx.x;

    // Stage pixel exp-quads: input rows ho..ho+4 (ho<=59 -> row<=63), all c.
    for (int i = t; i < PQ_ELEMS; i += 512) {
        int w = i & 63;
        int cr = i >> 6; // c*KK + r
        int c = cr / KK, r = cr - c * KK;
        float v = x[((n * CC + c) * HH + (ho + r)) * WW + w];
        float e1 = __expf(v), e2 = __expf(-v);
        pq[i] = (v4f){e1, v * e1, e2, -v * e2};
    }
    __syncthreads();

    int lane = t & 63;  // w position (60 used)
    int wid = t >> 6;   // 0..7
    int cw = wid & 3;   // channel owned by this wave
    int fgl = wid >> 2; // local feature quad: features fgh*8+fgl*4 .. +3

    // Wave-uniform weight base, forced scalar so loads become s_load.
    int wbi = __builtin_amdgcn_readfirstlane(((fgh * 2 + fgl) * PP + cw) * 16);
    const float* wb = wq + wbi;

    float d1[4] = {0.f, 0.f, 0.f, 0.f}, n1[4] = {0.f, 0.f, 0.f, 0.f};
    float d2[4] = {0.f, 0.f, 0.f, 0.f}, n2[4] = {0.f, 0.f, 0.f, 0.f};

    const v4f* pbase = pq + (cw * KK) * 64 + lane;

#pragma unroll 1
    for (int kh = 0; kh < KK; ++kh) {
        const v4f* prow = pbase + kh * 64;
        // Batch the 5 pixel ds_reads for this kh (one lgkm group).
        v4f q[KK];
#pragma unroll
        for (int kw = 0; kw < KK; ++kw) q[kw] = prow[kw];
#pragma unroll
        for (int kw = 0; kw < KK; ++kw) {
            // p = (kh*KK + kw)*CC + cw; record = 64 floats per (kh,kw) step.
            const float* wp = wb + (kh * KK + kw) * (CC * 16);
            v4f qv = q[kw];
#pragma unroll
            for (int j = 0; j < 4; ++j) {
                float ea1 = wp[j], ba1 = wp[4 + j];   // s_load operands
                float ea2 = wp[8 + j], bb2 = wp[12 + j];
                d1[j] = fmaf(qv.x, ea1, d1[j]);
                n1[j] = fmaf(qv.y, ea1, n1[j]);
                n1[j] = fmaf(qv.x, ba1, n1[j]);
                d2[j] = fmaf(qv.z, ea2, d2[j]);
                n2[j] = fmaf(qv.w, ea2, n2[j]);
                n2[j] = fmaf(qv.z, bb2, n2[j]);
            }
        }
    }

    // 4-way c-reduction via LDS overlay (pq dead; needs 1536 v4f).
    // red[(cw-1)*2+fgl][acc 0..3][lane]; accs pack d1/n1/d2/n2 (4f each).
    v4f* red = lds;
    __syncthreads();
    if (cw) {
        v4f* rr = red + (((cw - 1) * 2 + fgl) * 4) * 64 + lane;
        rr[0 * 64] = (v4f){d1[0], d1[1], d1[2], d1[3]};
        rr[1 * 64] = (v4f){n1[0], n1[1], n1[2], n1[3]};
        rr[2 * 64] = (v4f){d2[0], d2[1], d2[2], d2[3]};
        rr[3 * 64] = (v4f){n2[0], n2[1], n2[2], n2[3]};
    }
    __syncthreads();
    if (!cw && lane < WO) {
#pragma unroll
        for (int rcw = 0; rcw < 3; ++rcw) {
            const v4f* rr = red + ((rcw * 2 + fgl) * 4) * 64 + lane;
            v4f t0 = rr[0 * 64], t1 = rr[1 * 64];
            v4f t2 = rr[2 * 64], t3 = rr[3 * 64];
#pragma unroll
            for (int j = 0; j < 4; ++j) {
                d1[j] += t0[j]; n1[j] += t1[j];
                d2[j] += t2[j]; n2[j] += t3[j];
            }
        }
        int f0 = (fgh * 2 + fgl) * 4;
#pragma unroll
        for (int j = 0; j < 4; ++j) {
            float o = n1[j] / d1[j] + n2[j] / d2[j] + bias[f0 + j];
            out[((size_t)(n * FF + f0 + j) * HO + ho) * WO + lane] = o;
        }
    }
}

extern "C" void kernel_launch(void* const* d_in, const int* in_sizes, int n_in,
                              void* d_out, int out_size, void* d_ws, size_t ws_size,
                              hipStream_t stream) {
    const float* x    = (const float*)d_in[0];
    const float* k1   = (const float*)d_in[1];
    const float* k2   = (const float*)d_in[2];
    const float* bias = (const float*)d_in[3];
    float* out = (float*)d_out;
    float* wq = (float*)d_ws; // 4*100*16 floats = 25.6 KB

    smorph_weights<<<(4 * PP * 16 + 255) / 256, 256, 0, stream>>>(k1, k2, wq);
    // 960 blocks = 8 n x 60 ho x 2 f-halves; 512 threads = 8 waves
    // (4 channels x 2 f-quads); weights via scalar pipe, pixels via LDS.
    smorph_conv<<<NN * HO * 2, 512, 0, stream>>>(x, wq, bias, out);
}